// Round 11
// baseline (225.780 us; speedup 1.0000x reference)
//
#include <hip/hip_runtime.h>
#include <hip/hip_bf16.h>

// MoCo loss on MI355X. V=2, N=1024, D=128, K=65536, fp32 in, 2 fp32 scalars out.
// R19: 2 launches + 4B memset (cooperative launch failed under graph capture
// in R18 -> out never written; replaced with deadlock-free last-block pattern).
//   memset: counter (ws float idx 4096) = 0
//   conv_k (1024): R16-verified fp32-LDS conv (R17's 512-block conv was ~15us
//                  slower by remainder analysis). Blocks 0-7 zero QS.
//   mega_k (1568): intra [0,512) | loss1 [512,544) | queue R2-EXACT [544,1568)
//                  + LAST-BLOCK-DONE final reduce tail: threadfence ->
//                  atomicAdd(counter) -> block #1568 reduces IPart+QS+l1part
//                  and writes out. No spin barrier -> no deadlock risk.
// Launch-overhead model (validated): ~20us/launch. R6 4L rem=82, R16 3L
// rem=62, R17 3L+slow-conv rem=77. This round: 2 launches.
//
// loss2 row sums: den += exp(-c), num += c*exp(-c), c = 2-2*dot.
// QS atomics: ws[row] += Se, ws[1024+row] += 2*(Se-Sde).
//
// ws floats:
//   [0,2048)        QS_e[1024], QS_ce[1024]   (atomic accum)
//   [4096]          done-counter (memset per launch)
//   [6144,8192)     l1part[2048]
//   [139264,172032) IPart[16][2][1024]  slot = x*8+yg
//   byte 2 MB+:     Bblk (bf16, 16 MB)
//
// MFMA 16x16x32 bf16: A[m=lane&15][k=quad*8+j]; B[k=quad*8+j][n=lane&15];
// C: col=lane&15, row=quad*4+reg.
// Bblk[(tile*4+kk)*512 + (quad*16+n)*8 + j] = bf16(queue[kk*32+quad*8+j][tile*16+n])

#define NROWS 1024
#define DDIM  128
#define KQ    65536
#define NTILE 4096
#define SLICE 512           // tiles per XCD slice
#define SUB   4
#define IPART 139264
#define CNT_OFF 4096
#define BBLK_BYTE_OFF (2u*1024u*1024u)
#define TWO_LOG2E 2.8853900817779268f

#define MB_INTRA 512
#define MB_L1    544
#define MB_TOTAL (MB_L1 + 1024)   // 1568

typedef __attribute__((ext_vector_type(8))) short  short8;
typedef __attribute__((ext_vector_type(4))) float  float4v;

#if __has_builtin(__builtin_amdgcn_exp2f)
#define EXP2(x) __builtin_amdgcn_exp2f(x)
#else
#define EXP2(x) __expf((x) * 0.6931471805599453f)
#endif

__device__ __forceinline__ unsigned short f2bf(float f) {
  unsigned u = __float_as_uint(f);
  u += 0x7FFF + ((u >> 16) & 1);           // RNE
  return (unsigned short)(u >> 16);
}

__device__ __forceinline__ short8 cvt8(const float* __restrict__ p) {
  float4 a = *(const float4*)p;
  float4 b = *(const float4*)(p + 4);
  short8 r;
  r[0] = (short)f2bf(a.x); r[1] = (short)f2bf(a.y);
  r[2] = (short)f2bf(a.z); r[3] = (short)f2bf(a.w);
  r[4] = (short)f2bf(b.x); r[5] = (short)f2bf(b.y);
  r[6] = (short)f2bf(b.z); r[7] = (short)f2bf(b.w);
  return r;
}

__device__ __forceinline__ float wave_sum(float v) {
  #pragma unroll
  for (int o = 32; o > 0; o >>= 1) v += __shfl_down(v, o, 64);
  return v;
}

__global__ void zero_ws(float* __restrict__ ws) {
  ws[blockIdx.x * 256 + threadIdx.x] = 0.f;   // fallback only
}

// ---------- conv_k: R16-verified. 1024 blocks, 64col x 128d window ----------

__global__ __launch_bounds__(256) void conv_k(
    const float* __restrict__ queue, unsigned short* __restrict__ Bblk,
    float* __restrict__ ws) {
  __shared__ float lf[128][65];
  const int b   = (int)blockIdx.x;          // 0..1023
  const int tid = (int)threadIdx.x;
  if (b < 8) ws[b * 256 + tid] = 0.f;       // zero QS region
  const int xcd   = b & 7;
  const int idx   = b >> 3;                 // 0..127
  const int c0    = xcd * (SLICE * 16) + idx * 64;
  const int tile0 = xcd * SLICE + idx * 4;

  const int rl = tid >> 4;                  // 0..15
  const int cl = (tid & 15) * 4;            // 0..60
  #pragma unroll
  for (int p = 0; p < 8; ++p) {
    const int d = p * 16 + rl;
    float4 v = *(const float4*)(queue + (size_t)d * KQ + c0 + cl);
    lf[d][cl + 0] = v.x; lf[d][cl + 1] = v.y;
    lf[d][cl + 2] = v.z; lf[d][cl + 3] = v.w;
  }
  __syncthreads();
  #pragma unroll
  for (int s = 0; s < 4; ++s) {
    const int kk2  = tid >> 6;              // 0..3
    const int e8   = tid & 63;              // quad*16+n
    const int q2   = e8 >> 4, n = e8 & 15;
    const int dbase = kk2 * 32 + q2 * 8;
    const int col   = s * 16 + n;
    short8 sv;
    #pragma unroll
    for (int j = 0; j < 8; ++j) sv[j] = (short)f2bf(lf[dbase + j][col]);
    *(short8*)(Bblk + ((size_t)(tile0 + s) * 4 + kk2) * 512 + e8 * 8) = sv;
  }
}

// ---------- mega: intra | loss1 | queue + last-block final ----------

__global__ __launch_bounds__(256) void mega_k(
    const float* __restrict__ q, const float* __restrict__ kin,
    const unsigned short* __restrict__ Bblk, float* __restrict__ ws,
    float* __restrict__ out) {
  __shared__ float l_e[4][32], l_de[4][32];
  __shared__ float red1[256], red2[256];
  __shared__ int lastBlk;
  const int b    = (int)blockIdx.x;
  const int tid  = (int)threadIdx.x;
  const int lane = tid & 63;
  const int wave = tid >> 6;
  const int quad = lane >> 4;
  const int m    = lane & 15;

  if (b >= MB_L1) {
    // ---- queue GEMM: R2-EXACT shape (verified, 50.4us/56VGPR anchor)
    const int fb      = b - MB_L1;            // 544 % 8 == 0 keeps swizzle
    const int xcd     = fb & 7;
    const int t       = fb >> 3;
    const int rowBase = (t & 31) * 32;
    const int sub     = t >> 5;               // 0..3

    short8 a[2][4];
    #pragma unroll
    for (int rg = 0; rg < 2; ++rg)
      #pragma unroll
      for (int kk = 0; kk < 4; ++kk)
        a[rg][kk] = cvt8(q + (size_t)(rowBase + rg * 16 + m) * DDIM + kk * 32 + quad * 8);

    float ae[2][4] = {}, ade[2][4] = {};

    int wt = xcd * SLICE + sub * 4 + wave;
    const int wtEnd = (xcd + 1) * SLICE;
    short8 bc[4];
    {
      const unsigned short* bp = Bblk + (size_t)wt * 2048 + lane * 8;
      #pragma unroll
      for (int kk = 0; kk < 4; ++kk) bc[kk] = *(const short8*)(bp + kk * 512);
    }
    while (true) {
      const int wtn = wt + SUB * 4;
      const bool more = wtn < wtEnd;
      short8 bn[4];
      if (more) {
        const unsigned short* bp = Bblk + (size_t)wtn * 2048 + lane * 8;
        #pragma unroll
        for (int kk = 0; kk < 4; ++kk) bn[kk] = *(const short8*)(bp + kk * 512);
      }
      #pragma unroll
      for (int rg = 0; rg < 2; ++rg) {
        float4v C = {0.f, 0.f, 0.f, 0.f};
        #pragma unroll
        for (int kk = 0; kk < 4; ++kk)
          C = __builtin_amdgcn_mfma_f32_16x16x32_bf16(a[rg][kk], bc[kk], C, 0, 0, 0);
        #pragma unroll
        for (int r = 0; r < 4; ++r) {
          float d = C[r];
          float e = EXP2(fmaf(d, TWO_LOG2E, -TWO_LOG2E));
          ae[rg][r] += e;
          ade[rg][r] = fmaf(d, e, ade[rg][r]);
        }
      }
      if (!more) break;
      wt = wtn;
      #pragma unroll
      for (int kk = 0; kk < 4; ++kk) bc[kk] = bn[kk];
    }

    #pragma unroll
    for (int rg = 0; rg < 2; ++rg)
      #pragma unroll
      for (int r = 0; r < 4; ++r) {
        float e = ae[rg][r], de = ade[rg][r];
        #pragma unroll
        for (int mk = 8; mk >= 1; mk >>= 1) {
          e  += __shfl_xor(e,  mk, 64);
          de += __shfl_xor(de, mk, 64);
        }
        if (m == 0) {
          l_e[wave][rg * 16 + quad * 4 + r]  = e;
          l_de[wave][rg * 16 + quad * 4 + r] = de;
        }
      }
    __syncthreads();
    if (tid < 32) {
      float E = l_e[0][tid] + l_e[1][tid] + l_e[2][tid] + l_e[3][tid];
      float D = l_de[0][tid] + l_de[1][tid] + l_de[2][tid] + l_de[3][tid];
      const int row = rowBase + tid;
      atomicAdd(&ws[row],        E);
      atomicAdd(&ws[1024 + row], 2.f * (E - D));
    }
  } else if (b < MB_INTRA) {
    // ---- intra 2-rg (verified): b = rowblk | yg<<5 | x<<8
    const int rowblk = b & 31;
    const int yg = (b >> 5) & 7;
    const int x  = b >> 8;
    const float* qx = q + (size_t)x * NROWS * DDIM;
    const int rowBase = rowblk * 32;

    short8 a[2][4];
    #pragma unroll
    for (int rg = 0; rg < 2; ++rg)
      #pragma unroll
      for (int kk = 0; kk < 4; ++kk)
        a[rg][kk] = cvt8(qx + (size_t)(rowBase + rg * 16 + m) * DDIM + kk * 32 + quad * 8);

    float ae[2][4] = {}, ade[2][4] = {};
    for (int jt = yg * 4 + wave; jt < NROWS / 16; jt += 32) {
      short8 bfr[4];
      #pragma unroll
      for (int kk = 0; kk < 4; ++kk)
        bfr[kk] = cvt8(qx + (size_t)(jt * 16 + m) * DDIM + kk * 32 + quad * 8);
      const int dgRg = (jt * 16 - rowBase) >> 4;
      #pragma unroll
      for (int rg = 0; rg < 2; ++rg) {
        float4v C = {0.f, 0.f, 0.f, 0.f};
        #pragma unroll
        for (int kk = 0; kk < 4; ++kk)
          C = __builtin_amdgcn_mfma_f32_16x16x32_bf16(a[rg][kk], bfr[kk], C, 0, 0, 0);
        #pragma unroll
        for (int r = 0; r < 4; ++r) {
          float d = C[r];
          float e = EXP2(fmaf(d, TWO_LOG2E, -TWO_LOG2E));
          float de = d * e;
          if (rg == dgRg && (quad * 4 + r) == m) { e = 0.f; de = 0.f; }
          ae[rg][r] += e;
          ade[rg][r] += de;
        }
      }
    }
    #pragma unroll
    for (int rg = 0; rg < 2; ++rg)
      #pragma unroll
      for (int r = 0; r < 4; ++r) {
        float e = ae[rg][r], de = ade[rg][r];
        #pragma unroll
        for (int mk = 8; mk >= 1; mk >>= 1) {
          e  += __shfl_xor(e,  mk, 64);
          de += __shfl_xor(de, mk, 64);
        }
        if (m == 0) {
          l_e[wave][rg * 16 + quad * 4 + r]  = e;
          l_de[wave][rg * 16 + quad * 4 + r] = de;
        }
      }
    __syncthreads();
    if (tid < 32) {
      float E = l_e[0][tid] + l_e[1][tid] + l_e[2][tid] + l_e[3][tid];
      float D = l_de[0][tid] + l_de[1][tid] + l_de[2][tid] + l_de[3][tid];
      const int slot = x * 8 + yg;
      ws[IPART + (size_t)slot * 2048 + rowBase + tid]        = E;
      ws[IPART + (size_t)slot * 2048 + 1024 + rowBase + tid] = D;
    }
  } else {
    // ---- loss1 (verified): wave handles 16 (x,i) rows
    const int gw0 = (b - MB_INTRA) * 4 + wave;   // 0..127
    for (int t = 0; t < 16; ++t) {
      const int idx = gw0 * 16 + t;              // 0..2047
      const int x = idx >> 10;
      const int i = idx & 1023;
      const float2* qp = (const float2*)(q + (size_t)(x * NROWS + i) * DDIM);
      const float2* kp = (const float2*)(kin + (size_t)((1 - x) * NROWS + i) * DDIM);
      float2 av = qp[lane];
      float2 bv = kp[lane];
      float s = wave_sum(av.x * bv.x + av.y * bv.y);
      if (lane == 0) ws[6144 + idx] = s;
    }
  }

  // ---------- last-block-done final reduce ----------
  __threadfence();                 // release this block's writes (device scope)
  __syncthreads();                 // all threads' fences retired
  if (tid == 0) {
    unsigned old = atomicAdd((unsigned*)&ws[CNT_OFF], 1u);
    lastBlk = (old == (unsigned)(MB_TOTAL - 1)) ? 1 : 0;
  }
  __syncthreads();
  if (lastBlk) {
    __threadfence();               // acquire other blocks' writes
    const float* l1part = ws + 6144;
    float p1 = 0.f, p2 = 0.f;
    for (int idx = tid; idx < 2048; idx += 256) {
      int x = idx >> 10;
      int i = idx & 1023;
      p1 += 2.f - 2.f * l1part[idx];
      float E = 0.f, D = 0.f;
      #pragma unroll
      for (int g = 0; g < 8; ++g) {
        const int s = x * 8 + g;
        E += ws[IPART + (size_t)s * 2048 + i];
        D += ws[IPART + (size_t)s * 2048 + 1024 + i];
      }
      float den = ws[i]        + E;
      float num = ws[1024 + i] + 2.f * (E - D);
      p2 += num / den;
    }
    red1[tid] = p1;
    red2[tid] = p2;
    __syncthreads();
    for (int s = 128; s > 0; s >>= 1) {
      if (tid < s) {
        red1[tid] += red1[tid + s];
        red2[tid] += red2[tid + s];
      }
      __syncthreads();
    }
    if (tid == 0) {
      out[0] = red1[0] * (1.f / (2.f * NROWS));
      out[1] = -red2[0] * (1.f / (2.f * NROWS));
    }
  }
}

// ---------- fallback (ws too small for full Bblk) ----------

__global__ void conv_B_ck(const float* __restrict__ queue,
                          unsigned short* __restrict__ Bblk, int c0chunk) {
  const int tid  = (int)threadIdx.x;
  const int g    = tid >> 4;
  const int ci   = (tid & 15) * 4;
  const int cloc = (int)blockIdx.x * 64 + ci;
  const int c    = c0chunk + cloc;
  const int d0   = g * 8;
  const int kk   = g >> 2;
  const int quad = g & 3;
  float4v v[8];
  #pragma unroll
  for (int dd = 0; dd < 8; ++dd)
    v[dd] = *(const float4v*)(queue + (size_t)(d0 + dd) * KQ + c);
  unsigned short* outp = Bblk + ((size_t)(cloc >> 4) * 4 + kk) * 512
                              + (quad * 16 + (cloc & 15)) * 8;
  #pragma unroll
  for (int n = 0; n < 4; ++n) {
    short8 s;
    #pragma unroll
    for (int dd = 0; dd < 8; ++dd)
      s[dd] = (short)f2bf(v[dd][n]);
    *(short8*)(outp + n * 8) = s;
  }
}

__global__ __launch_bounds__(256) void mfma_queue_ck(
    const float* __restrict__ q, const unsigned short* __restrict__ Bblk,
    int cnt, float* __restrict__ acc_e, float* __restrict__ acc_ce) {
  const int lane = (int)threadIdx.x & 63;
  const int wave = (int)threadIdx.x >> 6;
  const int quad = lane >> 4;
  const int m    = lane & 15;
  const int rowBase = (int)blockIdx.x * 64;

  short8 a[4][4];
  #pragma unroll
  for (int rg = 0; rg < 4; ++rg)
    #pragma unroll
    for (int kk = 0; kk < 4; ++kk)
      a[rg][kk] = cvt8(q + (size_t)(rowBase + rg * 16 + m) * DDIM + kk * 32 + quad * 8);

  float ae[4][4] = {}, ade[4][4] = {};
  const int stride = (int)gridDim.y * 4;
  int wt = (int)blockIdx.y * 4 + wave;
  if (wt < cnt) {
    short8 bc[4];
    {
      const unsigned short* bp = Bblk + (size_t)wt * 2048 + lane * 8;
      #pragma unroll
      for (int kk = 0; kk < 4; ++kk) bc[kk] = *(const short8*)(bp + kk * 512);
    }
    while (true) {
      const int wtn = wt + stride;
      const bool more = wtn < cnt;
      short8 bn[4];
      if (more) {
        const unsigned short* bp = Bblk + (size_t)wtn * 2048 + lane * 8;
        #pragma unroll
        for (int kk = 0; kk < 4; ++kk) bn[kk] = *(const short8*)(bp + kk * 512);
      }
      #pragma unroll
      for (int rg = 0; rg < 4; ++rg) {
        float4v C = {0.f, 0.f, 0.f, 0.f};
        #pragma unroll
        for (int kk = 0; kk < 4; ++kk)
          C = __builtin_amdgcn_mfma_f32_16x16x32_bf16(a[rg][kk], bc[kk], C, 0, 0, 0);
        #pragma unroll
        for (int r = 0; r < 4; ++r) {
          float d = C[r];
          float e = EXP2(fmaf(d, TWO_LOG2E, -TWO_LOG2E));
          ae[rg][r] += e;
          ade[rg][r] = fmaf(d, e, ade[rg][r]);
        }
      }
      if (!more) break;
      wt = wtn;
      #pragma unroll
      for (int kk = 0; kk < 4; ++kk) bc[kk] = bn[kk];
    }
  }
  #pragma unroll
  for (int rg = 0; rg < 4; ++rg)
    #pragma unroll
    for (int r = 0; r < 4; ++r) {
      float e = ae[rg][r], de = ade[rg][r];
      #pragma unroll
      for (int mk = 8; mk >= 1; mk >>= 1) {
        e  += __shfl_xor(e,  mk, 64);
        de += __shfl_xor(de, mk, 64);
      }
      if (m == 0) {
        int row = rowBase + rg * 16 + quad * 4 + r;
        atomicAdd(&acc_e[row],  e);
        atomicAdd(&acc_ce[row], 2.f * (e - de));
      }
    }
}

__global__ __launch_bounds__(256) void mfma_intra(
    const float* __restrict__ q, float* __restrict__ ws) {
  const int x  = (int)blockIdx.z;
  const int yg = (int)blockIdx.y;
  const float* qx = q + (size_t)x * NROWS * DDIM;
  const int lane = (int)threadIdx.x & 63;
  const int wave = (int)threadIdx.x >> 6;
  const int quad = lane >> 4;
  const int m    = lane & 15;
  const int rowBase = (int)blockIdx.x * 64;

  __shared__ float l_e[4][64], l_de[4][64];

  short8 a[4][4];
  #pragma unroll
  for (int rg = 0; rg < 4; ++rg)
    #pragma unroll
    for (int kk = 0; kk < 4; ++kk)
      a[rg][kk] = cvt8(qx + (size_t)(rowBase + rg * 16 + m) * DDIM + kk * 32 + quad * 8);

  float ae[4][4] = {}, ade[4][4] = {};
  for (int jt = yg * 4 + wave; jt < NROWS / 16; jt += 32) {
    short8 bfr[4];
    #pragma unroll
    for (int kk = 0; kk < 4; ++kk)
      bfr[kk] = cvt8(qx + (size_t)(jt * 16 + m) * DDIM + kk * 32 + quad * 8);
    const int dgRg = (jt * 16 - rowBase) >> 4;
    #pragma unroll
    for (int rg = 0; rg < 4; ++rg) {
      float4v C = {0.f, 0.f, 0.f, 0.f};
      #pragma unroll
      for (int kk = 0; kk < 4; ++kk)
        C = __builtin_amdgcn_mfma_f32_16x16x32_bf16(a[rg][kk], bfr[kk], C, 0, 0, 0);
      #pragma unroll
      for (int r = 0; r < 4; ++r) {
        float d = C[r];
        float e = EXP2(fmaf(d, TWO_LOG2E, -TWO_LOG2E));
        float de = d * e;
        if (rg == dgRg && (quad * 4 + r) == m) { e = 0.f; de = 0.f; }
        ae[rg][r] += e;
        ade[rg][r] += de;
      }
    }
  }
  #pragma unroll
  for (int rg = 0; rg < 4; ++rg)
    #pragma unroll
    for (int r = 0; r < 4; ++r) {
      float e = ae[rg][r], de = ade[rg][r];
      #pragma unroll
      for (int mk = 8; mk >= 1; mk >>= 1) {
        e  += __shfl_xor(e,  mk, 64);
        de += __shfl_xor(de, mk, 64);
      }
      if (m == 0) {
        l_e[wave][rg * 16 + quad * 4 + r]  = e;
        l_de[wave][rg * 16 + quad * 4 + r] = de;
      }
    }
  __syncthreads();
  const int tid = (int)threadIdx.x;
  if (tid < 64) {
    float E = l_e[0][tid] + l_e[1][tid] + l_e[2][tid] + l_e[3][tid];
    float D = l_de[0][tid] + l_de[1][tid] + l_de[2][tid] + l_de[3][tid];
    const int slot = x * 8 + yg;
    ws[IPART + (size_t)slot * 2048 + rowBase + tid]        = E;
    ws[IPART + (size_t)slot * 2048 + 1024 + rowBase + tid] = D;
  }
}

__global__ void loss1_k(const float* __restrict__ q, const float* __restrict__ k,
                        float* __restrict__ l1part) {
  int gw   = (int)(blockIdx.x * blockDim.x + threadIdx.x) >> 6;
  int lane = (int)threadIdx.x & 63;
  int x = gw >> 10;
  int i = gw & 1023;
  const float2* qp = (const float2*)(q + (size_t)(x * NROWS + i) * DDIM);
  const float2* kp = (const float2*)(k + (size_t)((1 - x) * NROWS + i) * DDIM);
  float2 a = qp[lane];
  float2 b = kp[lane];
  float s = wave_sum(a.x * b.x + a.y * b.y);
  if (lane == 0) l1part[gw] = s;
}

__global__ __launch_bounds__(1024) void final3_k(const float* __restrict__ ws,
                                                 float* __restrict__ out) {
  const float* l1part = ws + 6144;
  __shared__ float red1[1024], red2[1024];
  const int tid = (int)threadIdx.x;
  float p1 = 0.f, p2 = 0.f;
  for (int idx = tid; idx < 2048; idx += 1024) {
    int x = idx >> 10;
    int i = idx & 1023;
    p1 += 2.f - 2.f * l1part[idx];
    float E = 0.f, D = 0.f;
    #pragma unroll
    for (int g = 0; g < 8; ++g) {
      const int s = x * 8 + g;
      E += ws[IPART + (size_t)s * 2048 + i];
      D += ws[IPART + (size_t)s * 2048 + 1024 + i];
    }
    float den = ws[i]        + E;
    float num = ws[1024 + i] + 2.f * (E - D);
    p2 += num / den;
  }
  red1[tid] = p1;
  red2[tid] = p2;
  __syncthreads();
  for (int s = 512; s > 0; s >>= 1) {
    if (tid < s) {
      red1[tid] += red1[tid + s];
      red2[tid] += red2[tid + s];
    }
    __syncthreads();
  }
  if (tid == 0) {
    out[0] = red1[0] * (1.f / (2.f * NROWS));
    out[1] = -red2[0] * (1.f / (2.f * NROWS));
  }
}

extern "C" void kernel_launch(void* const* d_in, const int* in_sizes, int n_in,
                              void* d_out, int out_size, void* d_ws, size_t ws_size,
                              hipStream_t stream) {
  const float* q     = (const float*)d_in[0];   // [2][1024][128]
  const float* k     = (const float*)d_in[1];   // [2][1024][128]
  const float* queue = (const float*)d_in[2];   // [128][65536]
  float* ws  = (float*)d_ws;
  float* out = (float*)d_out;
  unsigned short* Bblk = (unsigned short*)((char*)d_ws + BBLK_BYTE_OFF);

  const size_t needFull = BBLK_BYTE_OFF + (size_t)NTILE * 4096;   // 2MB hdr + 16MB
  if (ws_size >= needFull) {
    hipMemsetAsync((void*)(ws + CNT_OFF), 0, 4, stream);
    hipLaunchKernelGGL(conv_k, dim3(1024), dim3(256), 0, stream, queue, Bblk, ws);
    hipLaunchKernelGGL(mega_k, dim3(MB_TOTAL), dim3(256), 0, stream,
                       q, k, Bblk, ws, out);
  } else {
    // fallback: chunked queue path with atomics into QS (zeroed first)
    unsigned short* Bsmall = (unsigned short*)((char*)d_ws + 512 * 1024);
    hipLaunchKernelGGL(zero_ws, dim3(8), dim3(256), 0, stream, ws);
    hipLaunchKernelGGL(mfma_intra, dim3(16, 8, 2), dim3(256), 0, stream, q, ws);
    hipLaunchKernelGGL(loss1_k, dim3(512), dim3(256), 0, stream, q, k, ws + 6144);
    size_t avail = (ws_size > 512 * 1024) ? (ws_size - 512 * 1024) : 16384;
    int maxJt = (int)(avail / 4096);
    maxJt &= ~3;
    if (maxJt > NTILE) maxJt = NTILE;
    if (maxJt < 4) maxJt = 4;
    int nch = (NTILE + maxJt - 1) / maxJt;
    for (int c = 0; c < nch; ++c) {
      int jt0  = c * maxJt;
      int cntc = NTILE - jt0; if (cntc > maxJt) cntc = maxJt;
      hipLaunchKernelGGL(conv_B_ck, dim3(cntc / 4), dim3(256), 0, stream,
                         queue, Bsmall, jt0 * 16);
      int gy = (cntc + 3) / 4; if (gy > 64) gy = 64;
      hipLaunchKernelGGL(mfma_queue_ck, dim3(16, gy), dim3(256), 0, stream,
                         q, Bsmall, cntc, ws, ws + 1024);
    }
    hipLaunchKernelGGL(final3_k, dim3(1), dim3(1024), 0, stream, ws, out);
  }
}

// Round 12
// 136.191 us; speedup vs baseline: 1.6578x; 1.6578x over previous
//
#include <hip/hip_runtime.h>
#include <hip/hip_bf16.h>

// MoCo loss on MI355X. V=2, N=1024, D=128, K=65536, fp32 in, 2 fp32 scalars out.
// R20: 2 launches + 4B memset, FENCE-FREE last-block reduce.
// R19 lesson: __threadfence() by every thread = L2 writeback/invalidate storm
// (per-XCD L2s non-coherent -> release fence flushes cache-wide); mega 50->150us
// at SAME traffic. Fix: all cross-block partials are device-scope ATOMICS
// (bypass L2, complete at memory-side coherent point -- same pattern as the
// verified conv-zeros -> mega-atomicAdd QS path of R15/R17):
//   IPart, l1part writes -> atomicExch; QS -> atomicAdd (unchanged).
//   tail: __syncthreads (drains vmcnt -> atomics globally performed) ->
//   tid0 atomicAdd(counter) -> last block reduces with plain loads (lines
//   never cached this dispatch; dispatch-start invalidate kills replay stale).
//   conv_k: R16-verified fp32-LDS conv; blocks 0-7 zero QS.
//   mega_k: intra [0,512) | loss1 [512,544) | queue R2-EXACT [544,1568).
//
// loss2 row sums: den += exp(-c), num += c*exp(-c), c = 2-2*dot.
// QS atomics: ws[row] += Se, ws[1024+row] += 2*(Se-Sde).
//
// ws floats:
//   [0,2048)        QS_e[1024], QS_ce[1024]   (atomic accum)
//   [4096]          done-counter (memset per launch)
//   [6144,8192)     l1part[2048]              (atomicExch)
//   [139264,172032) IPart[16][2][1024]  slot = x*8+yg  (atomicExch)
//   byte 2 MB+:     Bblk (bf16, 16 MB)
//
// MFMA 16x16x32 bf16: A[m=lane&15][k=quad*8+j]; B[k=quad*8+j][n=lane&15];
// C: col=lane&15, row=quad*4+reg.
// Bblk[(tile*4+kk)*512 + (quad*16+n)*8 + j] = bf16(queue[kk*32+quad*8+j][tile*16+n])

#define NROWS 1024
#define DDIM  128
#define KQ    65536
#define NTILE 4096
#define SLICE 512           // tiles per XCD slice
#define SUB   4
#define IPART 139264
#define CNT_OFF 4096
#define BBLK_BYTE_OFF (2u*1024u*1024u)
#define TWO_LOG2E 2.8853900817779268f

#define MB_INTRA 512
#define MB_L1    544
#define MB_TOTAL (MB_L1 + 1024)   // 1568

typedef __attribute__((ext_vector_type(8))) short  short8;
typedef __attribute__((ext_vector_type(4))) float  float4v;

#if __has_builtin(__builtin_amdgcn_exp2f)
#define EXP2(x) __builtin_amdgcn_exp2f(x)
#else
#define EXP2(x) __expf((x) * 0.6931471805599453f)
#endif

__device__ __forceinline__ unsigned short f2bf(float f) {
  unsigned u = __float_as_uint(f);
  u += 0x7FFF + ((u >> 16) & 1);           // RNE
  return (unsigned short)(u >> 16);
}

__device__ __forceinline__ short8 cvt8(const float* __restrict__ p) {
  float4 a = *(const float4*)p;
  float4 b = *(const float4*)(p + 4);
  short8 r;
  r[0] = (short)f2bf(a.x); r[1] = (short)f2bf(a.y);
  r[2] = (short)f2bf(a.z); r[3] = (short)f2bf(a.w);
  r[4] = (short)f2bf(b.x); r[5] = (short)f2bf(b.y);
  r[6] = (short)f2bf(b.z); r[7] = (short)f2bf(b.w);
  return r;
}

__device__ __forceinline__ float wave_sum(float v) {
  #pragma unroll
  for (int o = 32; o > 0; o >>= 1) v += __shfl_down(v, o, 64);
  return v;
}

__global__ void zero_ws(float* __restrict__ ws) {
  ws[blockIdx.x * 256 + threadIdx.x] = 0.f;   // fallback only
}

// ---------- conv_k: R16-verified. 1024 blocks, 64col x 128d window ----------

__global__ __launch_bounds__(256) void conv_k(
    const float* __restrict__ queue, unsigned short* __restrict__ Bblk,
    float* __restrict__ ws) {
  __shared__ float lf[128][65];
  const int b   = (int)blockIdx.x;          // 0..1023
  const int tid = (int)threadIdx.x;
  if (b < 8) ws[b * 256 + tid] = 0.f;       // zero QS region
  const int xcd   = b & 7;
  const int idx   = b >> 3;                 // 0..127
  const int c0    = xcd * (SLICE * 16) + idx * 64;
  const int tile0 = xcd * SLICE + idx * 4;

  const int rl = tid >> 4;                  // 0..15
  const int cl = (tid & 15) * 4;            // 0..60
  #pragma unroll
  for (int p = 0; p < 8; ++p) {
    const int d = p * 16 + rl;
    float4 v = *(const float4*)(queue + (size_t)d * KQ + c0 + cl);
    lf[d][cl + 0] = v.x; lf[d][cl + 1] = v.y;
    lf[d][cl + 2] = v.z; lf[d][cl + 3] = v.w;
  }
  __syncthreads();
  #pragma unroll
  for (int s = 0; s < 4; ++s) {
    const int kk2  = tid >> 6;              // 0..3
    const int e8   = tid & 63;              // quad*16+n
    const int q2   = e8 >> 4, n = e8 & 15;
    const int dbase = kk2 * 32 + q2 * 8;
    const int col   = s * 16 + n;
    short8 sv;
    #pragma unroll
    for (int j = 0; j < 8; ++j) sv[j] = (short)f2bf(lf[dbase + j][col]);
    *(short8*)(Bblk + ((size_t)(tile0 + s) * 4 + kk2) * 512 + e8 * 8) = sv;
  }
}

// ---------- mega: intra | loss1 | queue + fence-free last-block final ----------

__global__ __launch_bounds__(256) void mega_k(
    const float* __restrict__ q, const float* __restrict__ kin,
    const unsigned short* __restrict__ Bblk, float* __restrict__ ws,
    float* __restrict__ out) {
  __shared__ float l_e[4][32], l_de[4][32];
  __shared__ float red1[256], red2[256];
  __shared__ int lastBlk;
  const int b    = (int)blockIdx.x;
  const int tid  = (int)threadIdx.x;
  const int lane = tid & 63;
  const int wave = tid >> 6;
  const int quad = lane >> 4;
  const int m    = lane & 15;

  if (b >= MB_L1) {
    // ---- queue GEMM: R2-EXACT shape (verified, 50.4us/56VGPR anchor)
    const int fb      = b - MB_L1;            // 544 % 8 == 0 keeps swizzle
    const int xcd     = fb & 7;
    const int t       = fb >> 3;
    const int rowBase = (t & 31) * 32;
    const int sub     = t >> 5;               // 0..3

    short8 a[2][4];
    #pragma unroll
    for (int rg = 0; rg < 2; ++rg)
      #pragma unroll
      for (int kk = 0; kk < 4; ++kk)
        a[rg][kk] = cvt8(q + (size_t)(rowBase + rg * 16 + m) * DDIM + kk * 32 + quad * 8);

    float ae[2][4] = {}, ade[2][4] = {};

    int wt = xcd * SLICE + sub * 4 + wave;
    const int wtEnd = (xcd + 1) * SLICE;
    short8 bc[4];
    {
      const unsigned short* bp = Bblk + (size_t)wt * 2048 + lane * 8;
      #pragma unroll
      for (int kk = 0; kk < 4; ++kk) bc[kk] = *(const short8*)(bp + kk * 512);
    }
    while (true) {
      const int wtn = wt + SUB * 4;
      const bool more = wtn < wtEnd;
      short8 bn[4];
      if (more) {
        const unsigned short* bp = Bblk + (size_t)wtn * 2048 + lane * 8;
        #pragma unroll
        for (int kk = 0; kk < 4; ++kk) bn[kk] = *(const short8*)(bp + kk * 512);
      }
      #pragma unroll
      for (int rg = 0; rg < 2; ++rg) {
        float4v C = {0.f, 0.f, 0.f, 0.f};
        #pragma unroll
        for (int kk = 0; kk < 4; ++kk)
          C = __builtin_amdgcn_mfma_f32_16x16x32_bf16(a[rg][kk], bc[kk], C, 0, 0, 0);
        #pragma unroll
        for (int r = 0; r < 4; ++r) {
          float d = C[r];
          float e = EXP2(fmaf(d, TWO_LOG2E, -TWO_LOG2E));
          ae[rg][r] += e;
          ade[rg][r] = fmaf(d, e, ade[rg][r]);
        }
      }
      if (!more) break;
      wt = wtn;
      #pragma unroll
      for (int kk = 0; kk < 4; ++kk) bc[kk] = bn[kk];
    }

    #pragma unroll
    for (int rg = 0; rg < 2; ++rg)
      #pragma unroll
      for (int r = 0; r < 4; ++r) {
        float e = ae[rg][r], de = ade[rg][r];
        #pragma unroll
        for (int mk = 8; mk >= 1; mk >>= 1) {
          e  += __shfl_xor(e,  mk, 64);
          de += __shfl_xor(de, mk, 64);
        }
        if (m == 0) {
          l_e[wave][rg * 16 + quad * 4 + r]  = e;
          l_de[wave][rg * 16 + quad * 4 + r] = de;
        }
      }
    __syncthreads();
    if (tid < 32) {
      float E = l_e[0][tid] + l_e[1][tid] + l_e[2][tid] + l_e[3][tid];
      float D = l_de[0][tid] + l_de[1][tid] + l_de[2][tid] + l_de[3][tid];
      const int row = rowBase + tid;
      atomicAdd(&ws[row],        E);
      atomicAdd(&ws[1024 + row], 2.f * (E - D));
    }
  } else if (b < MB_INTRA) {
    // ---- intra 2-rg (verified): b = rowblk | yg<<5 | x<<8
    const int rowblk = b & 31;
    const int yg = (b >> 5) & 7;
    const int x  = b >> 8;
    const float* qx = q + (size_t)x * NROWS * DDIM;
    const int rowBase = rowblk * 32;

    short8 a[2][4];
    #pragma unroll
    for (int rg = 0; rg < 2; ++rg)
      #pragma unroll
      for (int kk = 0; kk < 4; ++kk)
        a[rg][kk] = cvt8(qx + (size_t)(rowBase + rg * 16 + m) * DDIM + kk * 32 + quad * 8);

    float ae[2][4] = {}, ade[2][4] = {};
    for (int jt = yg * 4 + wave; jt < NROWS / 16; jt += 32) {
      short8 bfr[4];
      #pragma unroll
      for (int kk = 0; kk < 4; ++kk)
        bfr[kk] = cvt8(qx + (size_t)(jt * 16 + m) * DDIM + kk * 32 + quad * 8);
      const int dgRg = (jt * 16 - rowBase) >> 4;
      #pragma unroll
      for (int rg = 0; rg < 2; ++rg) {
        float4v C = {0.f, 0.f, 0.f, 0.f};
        #pragma unroll
        for (int kk = 0; kk < 4; ++kk)
          C = __builtin_amdgcn_mfma_f32_16x16x32_bf16(a[rg][kk], bfr[kk], C, 0, 0, 0);
        #pragma unroll
        for (int r = 0; r < 4; ++r) {
          float d = C[r];
          float e = EXP2(fmaf(d, TWO_LOG2E, -TWO_LOG2E));
          float de = d * e;
          if (rg == dgRg && (quad * 4 + r) == m) { e = 0.f; de = 0.f; }
          ae[rg][r] += e;
          ade[rg][r] += de;
        }
      }
    }
    #pragma unroll
    for (int rg = 0; rg < 2; ++rg)
      #pragma unroll
      for (int r = 0; r < 4; ++r) {
        float e = ae[rg][r], de = ade[rg][r];
        #pragma unroll
        for (int mk = 8; mk >= 1; mk >>= 1) {
          e  += __shfl_xor(e,  mk, 64);
          de += __shfl_xor(de, mk, 64);
        }
        if (m == 0) {
          l_e[wave][rg * 16 + quad * 4 + r]  = e;
          l_de[wave][rg * 16 + quad * 4 + r] = de;
        }
      }
    __syncthreads();
    if (tid < 32) {
      float E = l_e[0][tid] + l_e[1][tid] + l_e[2][tid] + l_e[3][tid];
      float D = l_de[0][tid] + l_de[1][tid] + l_de[2][tid] + l_de[3][tid];
      const int slot = x * 8 + yg;
      atomicExch(&ws[IPART + (size_t)slot * 2048 + rowBase + tid], E);
      atomicExch(&ws[IPART + (size_t)slot * 2048 + 1024 + rowBase + tid], D);
    }
  } else {
    // ---- loss1 (verified): wave handles 16 (x,i) rows
    const int gw0 = (b - MB_INTRA) * 4 + wave;   // 0..127
    for (int t = 0; t < 16; ++t) {
      const int idx = gw0 * 16 + t;              // 0..2047
      const int x = idx >> 10;
      const int i = idx & 1023;
      const float2* qp = (const float2*)(q + (size_t)(x * NROWS + i) * DDIM);
      const float2* kp = (const float2*)(kin + (size_t)((1 - x) * NROWS + i) * DDIM);
      float2 av = qp[lane];
      float2 bv = kp[lane];
      float s = wave_sum(av.x * bv.x + av.y * bv.y);
      if (lane == 0) atomicExch(&ws[6144 + idx], s);
    }
  }

  // ---------- fence-free last-block final reduce ----------
  // All cross-block data above was written with device-scope atomics
  // (coherent point). __syncthreads() forces vmcnt(0) per thread -> all this
  // block's atomics are globally performed before tid0's counter bump.
  __syncthreads();
  if (tid == 0) {
    unsigned old = atomicAdd((unsigned*)&ws[CNT_OFF], 1u);
    lastBlk = (old == (unsigned)(MB_TOTAL - 1)) ? 1 : 0;
  }
  __syncthreads();
  if (lastBlk) {
    const float* l1part = ws + 6144;
    float p1 = 0.f, p2 = 0.f;
    for (int idx = tid; idx < 2048; idx += 256) {
      int x = idx >> 10;
      int i = idx & 1023;
      p1 += 2.f - 2.f * l1part[idx];
      float E = 0.f, D = 0.f;
      #pragma unroll
      for (int g = 0; g < 8; ++g) {
        const int s = x * 8 + g;
        E += ws[IPART + (size_t)s * 2048 + i];
        D += ws[IPART + (size_t)s * 2048 + 1024 + i];
      }
      float den = ws[i]        + E;
      float num = ws[1024 + i] + 2.f * (E - D);
      p2 += num / den;
    }
    red1[tid] = p1;
    red2[tid] = p2;
    __syncthreads();
    for (int s = 128; s > 0; s >>= 1) {
      if (tid < s) {
        red1[tid] += red1[tid + s];
        red2[tid] += red2[tid + s];
      }
      __syncthreads();
    }
    if (tid == 0) {
      out[0] = red1[0] * (1.f / (2.f * NROWS));
      out[1] = -red2[0] * (1.f / (2.f * NROWS));
    }
  }
}

// ---------- fallback (ws too small for full Bblk) ----------

__global__ void conv_B_ck(const float* __restrict__ queue,
                          unsigned short* __restrict__ Bblk, int c0chunk) {
  const int tid  = (int)threadIdx.x;
  const int g    = tid >> 4;
  const int ci   = (tid & 15) * 4;
  const int cloc = (int)blockIdx.x * 64 + ci;
  const int c    = c0chunk + cloc;
  const int d0   = g * 8;
  const int kk   = g >> 2;
  const int quad = g & 3;
  float4v v[8];
  #pragma unroll
  for (int dd = 0; dd < 8; ++dd)
    v[dd] = *(const float4v*)(queue + (size_t)(d0 + dd) * KQ + c);
  unsigned short* outp = Bblk + ((size_t)(cloc >> 4) * 4 + kk) * 512
                              + (quad * 16 + (cloc & 15)) * 8;
  #pragma unroll
  for (int n = 0; n < 4; ++n) {
    short8 s;
    #pragma unroll
    for (int dd = 0; dd < 8; ++dd)
      s[dd] = (short)f2bf(v[dd][n]);
    *(short8*)(outp + n * 8) = s;
  }
}

__global__ __launch_bounds__(256) void mfma_queue_ck(
    const float* __restrict__ q, const unsigned short* __restrict__ Bblk,
    int cnt, float* __restrict__ acc_e, float* __restrict__ acc_ce) {
  const int lane = (int)threadIdx.x & 63;
  const int wave = (int)threadIdx.x >> 6;
  const int quad = lane >> 4;
  const int m    = lane & 15;
  const int rowBase = (int)blockIdx.x * 64;

  short8 a[4][4];
  #pragma unroll
  for (int rg = 0; rg < 4; ++rg)
    #pragma unroll
    for (int kk = 0; kk < 4; ++kk)
      a[rg][kk] = cvt8(q + (size_t)(rowBase + rg * 16 + m) * DDIM + kk * 32 + quad * 8);

  float ae[4][4] = {}, ade[4][4] = {};
  const int stride = (int)gridDim.y * 4;
  int wt = (int)blockIdx.y * 4 + wave;
  if (wt < cnt) {
    short8 bc[4];
    {
      const unsigned short* bp = Bblk + (size_t)wt * 2048 + lane * 8;
      #pragma unroll
      for (int kk = 0; kk < 4; ++kk) bc[kk] = *(const short8*)(bp + kk * 512);
    }
    while (true) {
      const int wtn = wt + stride;
      const bool more = wtn < cnt;
      short8 bn[4];
      if (more) {
        const unsigned short* bp = Bblk + (size_t)wtn * 2048 + lane * 8;
        #pragma unroll
        for (int kk = 0; kk < 4; ++kk) bn[kk] = *(const short8*)(bp + kk * 512);
      }
      #pragma unroll
      for (int rg = 0; rg < 4; ++rg) {
        float4v C = {0.f, 0.f, 0.f, 0.f};
        #pragma unroll
        for (int kk = 0; kk < 4; ++kk)
          C = __builtin_amdgcn_mfma_f32_16x16x32_bf16(a[rg][kk], bc[kk], C, 0, 0, 0);
        #pragma unroll
        for (int r = 0; r < 4; ++r) {
          float d = C[r];
          float e = EXP2(fmaf(d, TWO_LOG2E, -TWO_LOG2E));
          ae[rg][r] += e;
          ade[rg][r] = fmaf(d, e, ade[rg][r]);
        }
      }
      if (!more) break;
      wt = wtn;
      #pragma unroll
      for (int kk = 0; kk < 4; ++kk) bc[kk] = bn[kk];
    }
  }
  #pragma unroll
  for (int rg = 0; rg < 4; ++rg)
    #pragma unroll
    for (int r = 0; r < 4; ++r) {
      float e = ae[rg][r], de = ade[rg][r];
      #pragma unroll
      for (int mk = 8; mk >= 1; mk >>= 1) {
        e  += __shfl_xor(e,  mk, 64);
        de += __shfl_xor(de, mk, 64);
      }
      if (m == 0) {
        int row = rowBase + rg * 16 + quad * 4 + r;
        atomicAdd(&acc_e[row],  e);
        atomicAdd(&acc_ce[row], 2.f * (e - de));
      }
    }
}

__global__ __launch_bounds__(256) void mfma_intra(
    const float* __restrict__ q, float* __restrict__ ws) {
  const int x  = (int)blockIdx.z;
  const int yg = (int)blockIdx.y;
  const float* qx = q + (size_t)x * NROWS * DDIM;
  const int lane = (int)threadIdx.x & 63;
  const int wave = (int)threadIdx.x >> 6;
  const int quad = lane >> 4;
  const int m    = lane & 15;
  const int rowBase = (int)blockIdx.x * 64;

  __shared__ float l_e[4][64], l_de[4][64];

  short8 a[4][4];
  #pragma unroll
  for (int rg = 0; rg < 4; ++rg)
    #pragma unroll
    for (int kk = 0; kk < 4; ++kk)
      a[rg][kk] = cvt8(qx + (size_t)(rowBase + rg * 16 + m) * DDIM + kk * 32 + quad * 8);

  float ae[4][4] = {}, ade[4][4] = {};
  for (int jt = yg * 4 + wave; jt < NROWS / 16; jt += 32) {
    short8 bfr[4];
    #pragma unroll
    for (int kk = 0; kk < 4; ++kk)
      bfr[kk] = cvt8(qx + (size_t)(jt * 16 + m) * DDIM + kk * 32 + quad * 8);
    const int dgRg = (jt * 16 - rowBase) >> 4;
    #pragma unroll
    for (int rg = 0; rg < 4; ++rg) {
      float4v C = {0.f, 0.f, 0.f, 0.f};
      #pragma unroll
      for (int kk = 0; kk < 4; ++kk)
        C = __builtin_amdgcn_mfma_f32_16x16x32_bf16(a[rg][kk], bfr[kk], C, 0, 0, 0);
      #pragma unroll
      for (int r = 0; r < 4; ++r) {
        float d = C[r];
        float e = EXP2(fmaf(d, TWO_LOG2E, -TWO_LOG2E));
        float de = d * e;
        if (rg == dgRg && (quad * 4 + r) == m) { e = 0.f; de = 0.f; }
        ae[rg][r] += e;
        ade[rg][r] += de;
      }
    }
  }
  #pragma unroll
  for (int rg = 0; rg < 4; ++rg)
    #pragma unroll
    for (int r = 0; r < 4; ++r) {
      float e = ae[rg][r], de = ade[rg][r];
      #pragma unroll
      for (int mk = 8; mk >= 1; mk >>= 1) {
        e  += __shfl_xor(e,  mk, 64);
        de += __shfl_xor(de, mk, 64);
      }
      if (m == 0) {
        l_e[wave][rg * 16 + quad * 4 + r]  = e;
        l_de[wave][rg * 16 + quad * 4 + r] = de;
      }
    }
  __syncthreads();
  const int tid = (int)threadIdx.x;
  if (tid < 64) {
    float E = l_e[0][tid] + l_e[1][tid] + l_e[2][tid] + l_e[3][tid];
    float D = l_de[0][tid] + l_de[1][tid] + l_de[2][tid] + l_de[3][tid];
    const int slot = x * 8 + yg;
    ws[IPART + (size_t)slot * 2048 + rowBase + tid]        = E;
    ws[IPART + (size_t)slot * 2048 + 1024 + rowBase + tid] = D;
  }
}

__global__ void loss1_k(const float* __restrict__ q, const float* __restrict__ k,
                        float* __restrict__ l1part) {
  int gw   = (int)(blockIdx.x * blockDim.x + threadIdx.x) >> 6;
  int lane = (int)threadIdx.x & 63;
  int x = gw >> 10;
  int i = gw & 1023;
  const float2* qp = (const float2*)(q + (size_t)(x * NROWS + i) * DDIM);
  const float2* kp = (const float2*)(k + (size_t)((1 - x) * NROWS + i) * DDIM);
  float2 a = qp[lane];
  float2 b = kp[lane];
  float s = wave_sum(a.x * b.x + a.y * b.y);
  if (lane == 0) l1part[gw] = s;
}

__global__ __launch_bounds__(1024) void final3_k(const float* __restrict__ ws,
                                                 float* __restrict__ out) {
  const float* l1part = ws + 6144;
  __shared__ float red1[1024], red2[1024];
  const int tid = (int)threadIdx.x;
  float p1 = 0.f, p2 = 0.f;
  for (int idx = tid; idx < 2048; idx += 1024) {
    int x = idx >> 10;
    int i = idx & 1023;
    p1 += 2.f - 2.f * l1part[idx];
    float E = 0.f, D = 0.f;
    #pragma unroll
    for (int g = 0; g < 8; ++g) {
      const int s = x * 8 + g;
      E += ws[IPART + (size_t)s * 2048 + i];
      D += ws[IPART + (size_t)s * 2048 + 1024 + i];
    }
    float den = ws[i]        + E;
    float num = ws[1024 + i] + 2.f * (E - D);
    p2 += num / den;
  }
  red1[tid] = p1;
  red2[tid] = p2;
  __syncthreads();
  for (int s = 512; s > 0; s >>= 1) {
    if (tid < s) {
      red1[tid] += red1[tid + s];
      red2[tid] += red2[tid + s];
    }
    __syncthreads();
  }
  if (tid == 0) {
    out[0] = red1[0] * (1.f / (2.f * NROWS));
    out[1] = -red2[0] * (1.f / (2.f * NROWS));
  }
}

extern "C" void kernel_launch(void* const* d_in, const int* in_sizes, int n_in,
                              void* d_out, int out_size, void* d_ws, size_t ws_size,
                              hipStream_t stream) {
  const float* q     = (const float*)d_in[0];   // [2][1024][128]
  const float* k     = (const float*)d_in[1];   // [2][1024][128]
  const float* queue = (const float*)d_in[2];   // [128][65536]
  float* ws  = (float*)d_ws;
  float* out = (float*)d_out;
  unsigned short* Bblk = (unsigned short*)((char*)d_ws + BBLK_BYTE_OFF);

  const size_t needFull = BBLK_BYTE_OFF + (size_t)NTILE * 4096;   // 2MB hdr + 16MB
  if (ws_size >= needFull) {
    hipMemsetAsync((void*)(ws + CNT_OFF), 0, 4, stream);
    hipLaunchKernelGGL(conv_k, dim3(1024), dim3(256), 0, stream, queue, Bblk, ws);
    hipLaunchKernelGGL(mega_k, dim3(MB_TOTAL), dim3(256), 0, stream,
                       q, k, Bblk, ws, out);
  } else {
    // fallback: chunked queue path with atomics into QS (zeroed first)
    unsigned short* Bsmall = (unsigned short*)((char*)d_ws + 512 * 1024);
    hipLaunchKernelGGL(zero_ws, dim3(8), dim3(256), 0, stream, ws);
    hipLaunchKernelGGL(mfma_intra, dim3(16, 8, 2), dim3(256), 0, stream, q, ws);
    hipLaunchKernelGGL(loss1_k, dim3(512), dim3(256), 0, stream, q, k, ws + 6144);
    size_t avail = (ws_size > 512 * 1024) ? (ws_size - 512 * 1024) : 16384;
    int maxJt = (int)(avail / 4096);
    maxJt &= ~3;
    if (maxJt > NTILE) maxJt = NTILE;
    if (maxJt < 4) maxJt = 4;
    int nch = (NTILE + maxJt - 1) / maxJt;
    for (int c = 0; c < nch; ++c) {
      int jt0  = c * maxJt;
      int cntc = NTILE - jt0; if (cntc > maxJt) cntc = maxJt;
      hipLaunchKernelGGL(conv_B_ck, dim3(cntc / 4), dim3(256), 0, stream,
                         queue, Bsmall, jt0 * 16);
      int gy = (cntc + 3) / 4; if (gy > 64) gy = 64;
      hipLaunchKernelGGL(mfma_queue_ck, dim3(16, gy), dim3(256), 0, stream,
                         q, Bsmall, cntc, ws, ws + 1024);
    }
    hipLaunchKernelGGL(final3_k, dim3(1), dim3(1024), 0, stream, ws, out);
  }
}

// Round 13
// 128.712 us; speedup vs baseline: 1.7541x; 1.0581x over previous
//
#include <hip/hip_runtime.h>
#include <hip/hip_bf16.h>

// MoCo loss on MI355X. V=2, N=1024, D=128, K=65536, fp32 in, 2 fp32 scalars out.
// R21 = R17-exact restore (session best, 127.7us verified).
// Unified timing model (fits all passing rounds): ~65us FIXED harness
// reset/re-poison cost per iteration + queue-mega 50.4 + conv ~8-11 +
// final ~3-5. Queue loop pinned at 50-60us across SIX structural variants
// (occupancy x2 [R13], 2-deep prefetch [R15], LDS-share+barrier [R14],
// 4-rg intensity [R16], SUB8 [R13], atomic-tail [R20]) -> structural plateau.
// R20's in-kernel tail cost +9.6us on mega > launch saving -> reverted.
//   conv_k (512): 128col x 128d windows, contiguous 512B loads -> ushort LDS
//     -> exact Bblk chunks. Blocks 0-7 zero QS.
//   mega_k (1568): intra [0,512) | loss1 [512,544) | queue R2-EXACT [544,1568)
//     (2-rg, SUB=4, runtime-bounded 1-deep prefetch, 56 VGPR) atomic finish.
//   final3_k (1x1024): IPart reduce + loss2 + loss1 fold.
//
// loss2 row sums: den += exp(-c), num += c*exp(-c), c = 2-2*dot.
// QS atomics: ws[row] += Se, ws[1024+row] += 2*(Se-Sde).
//
// ws floats:
//   [0,2048)        QS_e[1024], QS_ce[1024]   (atomic accum)
//   [6144,8192)     l1part[2048]
//   [139264,172032) IPart[16][2][1024]  slot = x*8+yg
//   byte 2 MB+:     Bblk (bf16, 16 MB)
//
// MFMA 16x16x32 bf16: A[m=lane&15][k=quad*8+j]; B[k=quad*8+j][n=lane&15];
// C: col=lane&15, row=quad*4+reg.
// Bblk[(tile*4+kk)*512 + (quad*16+n)*8 + j] = bf16(queue[kk*32+quad*8+j][tile*16+n])

#define NROWS 1024
#define DDIM  128
#define KQ    65536
#define NTILE 4096
#define SLICE 512           // tiles per XCD slice
#define SUB   4
#define IPART 139264
#define BBLK_BYTE_OFF (2u*1024u*1024u)
#define TWO_LOG2E 2.8853900817779268f

#define MB_INTRA 512
#define MB_L1    544
#define MB_TOTAL (MB_L1 + 1024)

typedef __attribute__((ext_vector_type(8))) short  short8;
typedef __attribute__((ext_vector_type(4))) float  float4v;

#if __has_builtin(__builtin_amdgcn_exp2f)
#define EXP2(x) __builtin_amdgcn_exp2f(x)
#else
#define EXP2(x) __expf((x) * 0.6931471805599453f)
#endif

__device__ __forceinline__ unsigned short f2bf(float f) {
  unsigned u = __float_as_uint(f);
  u += 0x7FFF + ((u >> 16) & 1);           // RNE
  return (unsigned short)(u >> 16);
}

__device__ __forceinline__ short8 cvt8(const float* __restrict__ p) {
  float4 a = *(const float4*)p;
  float4 b = *(const float4*)(p + 4);
  short8 r;
  r[0] = (short)f2bf(a.x); r[1] = (short)f2bf(a.y);
  r[2] = (short)f2bf(a.z); r[3] = (short)f2bf(a.w);
  r[4] = (short)f2bf(b.x); r[5] = (short)f2bf(b.y);
  r[6] = (short)f2bf(b.z); r[7] = (short)f2bf(b.w);
  return r;
}

__device__ __forceinline__ float wave_sum(float v) {
  #pragma unroll
  for (int o = 32; o > 0; o >>= 1) v += __shfl_down(v, o, 64);
  return v;
}

__global__ void zero_ws(float* __restrict__ ws) {
  ws[blockIdx.x * 256 + threadIdx.x] = 0.f;   // fallback only
}

// ---------- conv_k: 512 blocks, 128col x 128d window each ----------

__global__ __launch_bounds__(256) void conv_k(
    const float* __restrict__ queue, unsigned short* __restrict__ Bblk,
    float* __restrict__ ws) {
  __shared__ unsigned short lsh[128][140];   // 35.8 KB, stride 140 (8B-aligned)
  const int b   = (int)blockIdx.x;           // 0..511
  const int tid = (int)threadIdx.x;
  if (b < 8) ws[b * 256 + tid] = 0.f;        // zero QS region
  const int xcd   = b & 7;
  const int w     = b >> 3;                  // 0..63
  const int c0    = xcd * 8192 + w * 128;
  const int tile0 = xcd * SLICE + w * 8;

  // phase 1: rows (tid>>5)+8s, cols (tid&31)*4 -> 512B contiguous per 32 lanes
  const int r0 = tid >> 5;                   // 0..7
  const int cc = (tid & 31) * 4;             // 0..124
  #pragma unroll
  for (int s = 0; s < 16; ++s) {
    const int r = r0 + s * 8;
    float4 v = *(const float4*)(queue + (size_t)r * KQ + c0 + cc);
    unsigned short u0 = f2bf(v.x), u1 = f2bf(v.y), u2 = f2bf(v.z), u3 = f2bf(v.w);
    *(ushort4*)(&lsh[r][cc]) = make_ushort4(u0, u1, u2, u3);
  }
  __syncthreads();

  // phase 2: 32 chunks (tl 0..7, kk 0..3); wave handles 8
  const int lane = tid & 63;
  const int wave = tid >> 6;
  const int quad = lane >> 4;
  const int n    = lane & 15;
  #pragma unroll
  for (int s2 = 0; s2 < 8; ++s2) {
    const int chunk = wave * 8 + s2;
    const int tl = chunk >> 2;
    const int kk = chunk & 3;
    const int dbase = kk * 32 + quad * 8;
    const int col   = tl * 16 + n;
    short8 sv;
    #pragma unroll
    for (int j = 0; j < 8; ++j) sv[j] = (short)lsh[dbase + j][col];
    *(short8*)(Bblk + ((size_t)(tile0 + tl) * 4 + kk) * 512 + lane * 8) = sv;
  }
}

// ---------- mega: intra [0,512) | loss1 [512,544) | queue [544,1568) ----------

__global__ __launch_bounds__(256) void mega_k(
    const float* __restrict__ q, const float* __restrict__ kin,
    const unsigned short* __restrict__ Bblk, float* __restrict__ ws) {
  __shared__ float l_e[4][32], l_de[4][32];
  const int b    = (int)blockIdx.x;
  const int tid  = (int)threadIdx.x;
  const int lane = tid & 63;
  const int wave = tid >> 6;
  const int quad = lane >> 4;
  const int m    = lane & 15;

  if (b >= MB_L1) {
    // ---- queue GEMM: R2-EXACT shape. 32-row blocks, SUB=4, 32 iters/wave.
    const int fb      = b - MB_L1;            // 544 % 8 == 0 keeps swizzle
    const int xcd     = fb & 7;
    const int t       = fb >> 3;
    const int rowBase = (t & 31) * 32;
    const int sub     = t >> 5;               // 0..3

    short8 a[2][4];
    #pragma unroll
    for (int rg = 0; rg < 2; ++rg)
      #pragma unroll
      for (int kk = 0; kk < 4; ++kk)
        a[rg][kk] = cvt8(q + (size_t)(rowBase + rg * 16 + m) * DDIM + kk * 32 + quad * 8);

    float ae[2][4] = {}, ade[2][4] = {};

    int wt = xcd * SLICE + sub * 4 + wave;
    const int wtEnd = (xcd + 1) * SLICE;
    short8 bc[4];
    {
      const unsigned short* bp = Bblk + (size_t)wt * 2048 + lane * 8;
      #pragma unroll
      for (int kk = 0; kk < 4; ++kk) bc[kk] = *(const short8*)(bp + kk * 512);
    }
    while (true) {
      const int wtn = wt + SUB * 4;
      const bool more = wtn < wtEnd;
      short8 bn[4];
      if (more) {
        const unsigned short* bp = Bblk + (size_t)wtn * 2048 + lane * 8;
        #pragma unroll
        for (int kk = 0; kk < 4; ++kk) bn[kk] = *(const short8*)(bp + kk * 512);
      }
      #pragma unroll
      for (int rg = 0; rg < 2; ++rg) {
        float4v C = {0.f, 0.f, 0.f, 0.f};
        #pragma unroll
        for (int kk = 0; kk < 4; ++kk)
          C = __builtin_amdgcn_mfma_f32_16x16x32_bf16(a[rg][kk], bc[kk], C, 0, 0, 0);
        #pragma unroll
        for (int r = 0; r < 4; ++r) {
          float d = C[r];
          float e = EXP2(fmaf(d, TWO_LOG2E, -TWO_LOG2E));
          ae[rg][r] += e;
          ade[rg][r] = fmaf(d, e, ade[rg][r]);
        }
      }
      if (!more) break;
      wt = wtn;
      #pragma unroll
      for (int kk = 0; kk < 4; ++kk) bc[kk] = bn[kk];
    }

    #pragma unroll
    for (int rg = 0; rg < 2; ++rg)
      #pragma unroll
      for (int r = 0; r < 4; ++r) {
        float e = ae[rg][r], de = ade[rg][r];
        #pragma unroll
        for (int mk = 8; mk >= 1; mk >>= 1) {
          e  += __shfl_xor(e,  mk, 64);
          de += __shfl_xor(de, mk, 64);
        }
        if (m == 0) {
          l_e[wave][rg * 16 + quad * 4 + r]  = e;
          l_de[wave][rg * 16 + quad * 4 + r] = de;
        }
      }
    __syncthreads();
    if (tid < 32) {
      float E = l_e[0][tid] + l_e[1][tid] + l_e[2][tid] + l_e[3][tid];
      float D = l_de[0][tid] + l_de[1][tid] + l_de[2][tid] + l_de[3][tid];
      const int row = rowBase + tid;
      atomicAdd(&ws[row],        E);
      atomicAdd(&ws[1024 + row], 2.f * (E - D));
    }
  } else if (b < MB_INTRA) {
    // ---- intra 2-rg (verified): b = rowblk | yg<<5 | x<<8
    const int rowblk = b & 31;
    const int yg = (b >> 5) & 7;
    const int x  = b >> 8;
    const float* qx = q + (size_t)x * NROWS * DDIM;
    const int rowBase = rowblk * 32;

    short8 a[2][4];
    #pragma unroll
    for (int rg = 0; rg < 2; ++rg)
      #pragma unroll
      for (int kk = 0; kk < 4; ++kk)
        a[rg][kk] = cvt8(qx + (size_t)(rowBase + rg * 16 + m) * DDIM + kk * 32 + quad * 8);

    float ae[2][4] = {}, ade[2][4] = {};
    for (int jt = yg * 4 + wave; jt < NROWS / 16; jt += 32) {
      short8 bfr[4];
      #pragma unroll
      for (int kk = 0; kk < 4; ++kk)
        bfr[kk] = cvt8(qx + (size_t)(jt * 16 + m) * DDIM + kk * 32 + quad * 8);
      const int dgRg = (jt * 16 - rowBase) >> 4;
      #pragma unroll
      for (int rg = 0; rg < 2; ++rg) {
        float4v C = {0.f, 0.f, 0.f, 0.f};
        #pragma unroll
        for (int kk = 0; kk < 4; ++kk)
          C = __builtin_amdgcn_mfma_f32_16x16x32_bf16(a[rg][kk], bfr[kk], C, 0, 0, 0);
        #pragma unroll
        for (int r = 0; r < 4; ++r) {
          float d = C[r];
          float e = EXP2(fmaf(d, TWO_LOG2E, -TWO_LOG2E));
          float de = d * e;
          if (rg == dgRg && (quad * 4 + r) == m) { e = 0.f; de = 0.f; }
          ae[rg][r] += e;
          ade[rg][r] += de;
        }
      }
    }
    #pragma unroll
    for (int rg = 0; rg < 2; ++rg)
      #pragma unroll
      for (int r = 0; r < 4; ++r) {
        float e = ae[rg][r], de = ade[rg][r];
        #pragma unroll
        for (int mk = 8; mk >= 1; mk >>= 1) {
          e  += __shfl_xor(e,  mk, 64);
          de += __shfl_xor(de, mk, 64);
        }
        if (m == 0) {
          l_e[wave][rg * 16 + quad * 4 + r]  = e;
          l_de[wave][rg * 16 + quad * 4 + r] = de;
        }
      }
    __syncthreads();
    if (tid < 32) {
      float E = l_e[0][tid] + l_e[1][tid] + l_e[2][tid] + l_e[3][tid];
      float D = l_de[0][tid] + l_de[1][tid] + l_de[2][tid] + l_de[3][tid];
      const int slot = x * 8 + yg;
      ws[IPART + (size_t)slot * 2048 + rowBase + tid]        = E;
      ws[IPART + (size_t)slot * 2048 + 1024 + rowBase + tid] = D;
    }
  } else {
    // ---- loss1 (verified): wave handles 16 (x,i) rows
    const int gw0 = (b - MB_INTRA) * 4 + wave;   // 0..127
    for (int t = 0; t < 16; ++t) {
      const int idx = gw0 * 16 + t;              // 0..2047
      const int x = idx >> 10;
      const int i = idx & 1023;
      const float2* qp = (const float2*)(q + (size_t)(x * NROWS + i) * DDIM);
      const float2* kp = (const float2*)(kin + (size_t)((1 - x) * NROWS + i) * DDIM);
      float2 av = qp[lane];
      float2 bv = kp[lane];
      float s = wave_sum(av.x * bv.x + av.y * bv.y);
      if (lane == 0) ws[6144 + idx] = s;
    }
  }
}

// ---------- final3: IPart reduce + loss2 + loss1 fold, 1024 threads ----------

__global__ __launch_bounds__(1024) void final3_k(const float* __restrict__ ws,
                                                 float* __restrict__ out) {
  const float* l1part = ws + 6144;
  __shared__ float red1[1024], red2[1024];
  const int tid = (int)threadIdx.x;
  float p1 = 0.f, p2 = 0.f;
  for (int idx = tid; idx < 2048; idx += 1024) {
    int x = idx >> 10;
    int i = idx & 1023;
    p1 += 2.f - 2.f * l1part[idx];
    float E = 0.f, D = 0.f;
    #pragma unroll
    for (int g = 0; g < 8; ++g) {
      const int s = x * 8 + g;
      E += ws[IPART + (size_t)s * 2048 + i];
      D += ws[IPART + (size_t)s * 2048 + 1024 + i];
    }
    float den = ws[i]        + E;
    float num = ws[1024 + i] + 2.f * (E - D);
    p2 += num / den;
  }
  red1[tid] = p1;
  red2[tid] = p2;
  __syncthreads();
  for (int s = 512; s > 0; s >>= 1) {
    if (tid < s) {
      red1[tid] += red1[tid + s];
      red2[tid] += red2[tid + s];
    }
    __syncthreads();
  }
  if (tid == 0) {
    out[0] = red1[0] * (1.f / (2.f * NROWS));
    out[1] = -red2[0] * (1.f / (2.f * NROWS));
  }
}

// ---------- chunked fallback (ws too small for full Bblk) ----------

__global__ void conv_B_ck(const float* __restrict__ queue,
                          unsigned short* __restrict__ Bblk, int c0chunk) {
  const int tid  = (int)threadIdx.x;
  const int g    = tid >> 4;
  const int ci   = (tid & 15) * 4;
  const int cloc = (int)blockIdx.x * 64 + ci;
  const int c    = c0chunk + cloc;
  const int d0   = g * 8;
  const int kk   = g >> 2;
  const int quad = g & 3;
  float4v v[8];
  #pragma unroll
  for (int dd = 0; dd < 8; ++dd)
    v[dd] = *(const float4v*)(queue + (size_t)(d0 + dd) * KQ + c);
  unsigned short* outp = Bblk + ((size_t)(cloc >> 4) * 4 + kk) * 512
                              + (quad * 16 + (cloc & 15)) * 8;
  #pragma unroll
  for (int n = 0; n < 4; ++n) {
    short8 s;
    #pragma unroll
    for (int dd = 0; dd < 8; ++dd)
      s[dd] = (short)f2bf(v[dd][n]);
    *(short8*)(outp + n * 8) = s;
  }
}

__global__ __launch_bounds__(256) void mfma_queue_ck(
    const float* __restrict__ q, const unsigned short* __restrict__ Bblk,
    int cnt, float* __restrict__ acc_e, float* __restrict__ acc_ce) {
  const int lane = (int)threadIdx.x & 63;
  const int wave = (int)threadIdx.x >> 6;
  const int quad = lane >> 4;
  const int m    = lane & 15;
  const int rowBase = (int)blockIdx.x * 64;

  short8 a[4][4];
  #pragma unroll
  for (int rg = 0; rg < 4; ++rg)
    #pragma unroll
    for (int kk = 0; kk < 4; ++kk)
      a[rg][kk] = cvt8(q + (size_t)(rowBase + rg * 16 + m) * DDIM + kk * 32 + quad * 8);

  float ae[4][4] = {}, ade[4][4] = {};
  const int stride = (int)gridDim.y * 4;
  int wt = (int)blockIdx.y * 4 + wave;
  if (wt < cnt) {
    short8 bc[4];
    {
      const unsigned short* bp = Bblk + (size_t)wt * 2048 + lane * 8;
      #pragma unroll
      for (int kk = 0; kk < 4; ++kk) bc[kk] = *(const short8*)(bp + kk * 512);
    }
    while (true) {
      const int wtn = wt + stride;
      const bool more = wtn < cnt;
      short8 bn[4];
      if (more) {
        const unsigned short* bp = Bblk + (size_t)wtn * 2048 + lane * 8;
        #pragma unroll
        for (int kk = 0; kk < 4; ++kk) bn[kk] = *(const short8*)(bp + kk * 512);
      }
      #pragma unroll
      for (int rg = 0; rg < 4; ++rg) {
        float4v C = {0.f, 0.f, 0.f, 0.f};
        #pragma unroll
        for (int kk = 0; kk < 4; ++kk)
          C = __builtin_amdgcn_mfma_f32_16x16x32_bf16(a[rg][kk], bc[kk], C, 0, 0, 0);
        #pragma unroll
        for (int r = 0; r < 4; ++r) {
          float d = C[r];
          float e = EXP2(fmaf(d, TWO_LOG2E, -TWO_LOG2E));
          ae[rg][r] += e;
          ade[rg][r] = fmaf(d, e, ade[rg][r]);
        }
      }
      if (!more) break;
      wt = wtn;
      #pragma unroll
      for (int kk = 0; kk < 4; ++kk) bc[kk] = bn[kk];
    }
  }
  #pragma unroll
  for (int rg = 0; rg < 4; ++rg)
    #pragma unroll
    for (int r = 0; r < 4; ++r) {
      float e = ae[rg][r], de = ade[rg][r];
      #pragma unroll
      for (int mk = 8; mk >= 1; mk >>= 1) {
        e  += __shfl_xor(e,  mk, 64);
        de += __shfl_xor(de, mk, 64);
      }
      if (m == 0) {
        int row = rowBase + rg * 16 + quad * 4 + r;
        atomicAdd(&acc_e[row],  e);
        atomicAdd(&acc_ce[row], 2.f * (e - de));
      }
    }
}

// fallback intra (4-rg)
__global__ __launch_bounds__(256) void mfma_intra(
    const float* __restrict__ q, float* __restrict__ ws) {
  const int x  = (int)blockIdx.z;
  const int yg = (int)blockIdx.y;
  const float* qx = q + (size_t)x * NROWS * DDIM;
  const int lane = (int)threadIdx.x & 63;
  const int wave = (int)threadIdx.x >> 6;
  const int quad = lane >> 4;
  const int m    = lane & 15;
  const int rowBase = (int)blockIdx.x * 64;

  __shared__ float l_e[4][64], l_de[4][64];

  short8 a[4][4];
  #pragma unroll
  for (int rg = 0; rg < 4; ++rg)
    #pragma unroll
    for (int kk = 0; kk < 4; ++kk)
      a[rg][kk] = cvt8(qx + (size_t)(rowBase + rg * 16 + m) * DDIM + kk * 32 + quad * 8);

  float ae[4][4] = {}, ade[4][4] = {};
  for (int jt = yg * 4 + wave; jt < NROWS / 16; jt += 32) {
    short8 bfr[4];
    #pragma unroll
    for (int kk = 0; kk < 4; ++kk)
      bfr[kk] = cvt8(qx + (size_t)(jt * 16 + m) * DDIM + kk * 32 + quad * 8);
    const int dgRg = (jt * 16 - rowBase) >> 4;
    #pragma unroll
    for (int rg = 0; rg < 4; ++rg) {
      float4v C = {0.f, 0.f, 0.f, 0.f};
      #pragma unroll
      for (int kk = 0; kk < 4; ++kk)
        C = __builtin_amdgcn_mfma_f32_16x16x32_bf16(a[rg][kk], bfr[kk], C, 0, 0, 0);
      #pragma unroll
      for (int r = 0; r < 4; ++r) {
        float d = C[r];
        float e = EXP2(fmaf(d, TWO_LOG2E, -TWO_LOG2E));
        float de = d * e;
        if (rg == dgRg && (quad * 4 + r) == m) { e = 0.f; de = 0.f; }
        ae[rg][r] += e;
        ade[rg][r] += de;
      }
    }
  }
  #pragma unroll
  for (int rg = 0; rg < 4; ++rg)
    #pragma unroll
    for (int r = 0; r < 4; ++r) {
      float e = ae[rg][r], de = ade[rg][r];
      #pragma unroll
      for (int mk = 8; mk >= 1; mk >>= 1) {
        e  += __shfl_xor(e,  mk, 64);
        de += __shfl_xor(de, mk, 64);
      }
      if (m == 0) {
        l_e[wave][rg * 16 + quad * 4 + r]  = e;
        l_de[wave][rg * 16 + quad * 4 + r] = de;
      }
    }
  __syncthreads();
  const int tid = (int)threadIdx.x;
  if (tid < 64) {
    float E = l_e[0][tid] + l_e[1][tid] + l_e[2][tid] + l_e[3][tid];
    float D = l_de[0][tid] + l_de[1][tid] + l_de[2][tid] + l_de[3][tid];
    const int slot = x * 8 + yg;
    ws[IPART + (size_t)slot * 2048 + rowBase + tid]        = E;
    ws[IPART + (size_t)slot * 2048 + 1024 + rowBase + tid] = D;
  }
}

__global__ void loss1_k(const float* __restrict__ q, const float* __restrict__ k,
                        float* __restrict__ l1part) {
  int gw   = (int)(blockIdx.x * blockDim.x + threadIdx.x) >> 6;
  int lane = (int)threadIdx.x & 63;
  int x = gw >> 10;
  int i = gw & 1023;
  const float2* qp = (const float2*)(q + (size_t)(x * NROWS + i) * DDIM);
  const float2* kp = (const float2*)(k + (size_t)((1 - x) * NROWS + i) * DDIM);
  float2 a = qp[lane];
  float2 b = kp[lane];
  float s = wave_sum(a.x * b.x + a.y * b.y);
  if (lane == 0) l1part[gw] = s;
}

extern "C" void kernel_launch(void* const* d_in, const int* in_sizes, int n_in,
                              void* d_out, int out_size, void* d_ws, size_t ws_size,
                              hipStream_t stream) {
  const float* q     = (const float*)d_in[0];   // [2][1024][128]
  const float* k     = (const float*)d_in[1];   // [2][1024][128]
  const float* queue = (const float*)d_in[2];   // [128][65536]
  float* ws  = (float*)d_ws;
  float* out = (float*)d_out;
  unsigned short* Bblk = (unsigned short*)((char*)d_ws + BBLK_BYTE_OFF);

  const size_t needFull = BBLK_BYTE_OFF + (size_t)NTILE * 4096;   // 2MB hdr + 16MB
  if (ws_size >= needFull) {
    hipLaunchKernelGGL(conv_k, dim3(512), dim3(256), 0, stream, queue, Bblk, ws);
    hipLaunchKernelGGL(mega_k, dim3(MB_TOTAL), dim3(256), 0, stream,
                       q, k, Bblk, ws);
    hipLaunchKernelGGL(final3_k, dim3(1), dim3(1024), 0, stream, ws, out);
  } else {
    // fallback: chunked queue path with atomics into QS (zeroed first)
    unsigned short* Bsmall = (unsigned short*)((char*)d_ws + 512 * 1024);
    hipLaunchKernelGGL(zero_ws, dim3(8), dim3(256), 0, stream, ws);
    hipLaunchKernelGGL(mfma_intra, dim3(16, 8, 2), dim3(256), 0, stream, q, ws);
    hipLaunchKernelGGL(loss1_k, dim3(512), dim3(256), 0, stream, q, k, ws + 6144);
    size_t avail = (ws_size > 512 * 1024) ? (ws_size - 512 * 1024) : 16384;
    int maxJt = (int)(avail / 4096);
    maxJt &= ~3;
    if (maxJt > NTILE) maxJt = NTILE;
    if (maxJt < 4) maxJt = 4;
    int nch = (NTILE + maxJt - 1) / maxJt;
    for (int c = 0; c < nch; ++c) {
      int jt0  = c * maxJt;
      int cntc = NTILE - jt0; if (cntc > maxJt) cntc = maxJt;
      hipLaunchKernelGGL(conv_B_ck, dim3(cntc / 4), dim3(256), 0, stream,
                         queue, Bsmall, jt0 * 16);
      int gy = (cntc + 3) / 4; if (gy > 64) gy = 64;
      hipLaunchKernelGGL(mfma_queue_ck, dim3(16, gy), dim3(256), 0, stream,
                         q, Bsmall, cntc, ws, ws + 1024);
    }
    hipLaunchKernelGGL(final3_k, dim3(1), dim3(1024), 0, stream, ws, out);
  }
}